// Round 1
// baseline (186.421 us; speedup 1.0000x reference)
//
#include <hip/hip_runtime.h>
#include <hip/hip_bf16.h>

// DecorrLoss: x (8,4096,512) fp32, kappa scalar ->
//   grad (512,512), correlation_loss (scalar), whitening_loss (scalar)
// out layout: [0..262143] grad, [262144] corr, [262145] whit
//
// Identities used:
//   corr  = sum_n (s2_n^2 - s4_n) / (N d^2)
//   whit  = sum_n (s4_n - 2 s2_n) / (N d^2) + 1/d      (since sum_i (x^2-1)^2 = s4 - 2 s2 + d)
//   grad  = (1-k)/N * gram  off-diag,  k*(gram_ii/N - 1) on diag,  gram = X^T X

#define D 512
#define NSAMP 32768
#define KPARTS 32
#define KC (NSAMP / KPARTS)  // 1024 samples per k-partition
#define BK 64
#define NCHUNK (KC / BK)     // 16 chunks per block

typedef __bf16 bf16x8 __attribute__((ext_vector_type(8)));
typedef float floatx4 __attribute__((ext_vector_type(4)));

__global__ __launch_bounds__(1024) void zero_kernel(float* out, int n) {
    int i = blockIdx.x * 1024 + threadIdx.x;
    if (i < n) out[i] = 0.0f;
}

// One wave per sample-row (512 floats); 512 blocks x 4 waves x 16 iterations = 32768 samples.
__global__ __launch_bounds__(256) void loss_kernel(const float* __restrict__ x,
                                                   float* __restrict__ out) {
    const int w = threadIdx.x >> 6;
    const int l = threadIdx.x & 63;
    const int gw = blockIdx.x * 4 + w;  // 0..2047
    float accA = 0.f;  // sum of s2^2 - s4
    float accB = 0.f;  // sum of s4 - 2*s2
    for (int it = 0; it < 16; ++it) {
        const float* row = x + (size_t)(gw + it * 2048) * D;
        float4 a = *(const float4*)(row + l * 4);
        float4 b = *(const float4*)(row + 256 + l * 4);
        float p2 = 0.f, p4 = 0.f, e;
        e = a.x * a.x; p2 += e; p4 += e * e;
        e = a.y * a.y; p2 += e; p4 += e * e;
        e = a.z * a.z; p2 += e; p4 += e * e;
        e = a.w * a.w; p2 += e; p4 += e * e;
        e = b.x * b.x; p2 += e; p4 += e * e;
        e = b.y * b.y; p2 += e; p4 += e * e;
        e = b.z * b.z; p2 += e; p4 += e * e;
        e = b.w * b.w; p2 += e; p4 += e * e;
#pragma unroll
        for (int m = 1; m < 64; m <<= 1) {
            p2 += __shfl_xor(p2, m);
            p4 += __shfl_xor(p4, m);
        }
        accA += p2 * p2 - p4;
        accB += p4 - 2.0f * p2;
    }
    if (l == 0) {
        const float SCALE = 1.1641532182693481e-10f;  // 1/(N*d*d) = 2^-33
        atomicAdd(out + D * D, accA * SCALE);
        atomicAdd(out + D * D + 1, accB * SCALE);
    }
    if (blockIdx.x == 0 && threadIdx.x == 0) {
        atomicAdd(out + D * D + 1, 0.001953125f);  // + N*d*SCALE = 1/d
    }
}

// Split-K bf16 MFMA Gram. Block = 256 thr (4 waves 2x2, each wave 64x64 via 4x4 of 16x16x32).
// LDS: [feature 0..127][k 0..63] bf16, row stride 128 B, 16B-chunk XOR-ish swizzle
// pc = (k_octet + (feat>>1)) & 7 -> uniform 8 lanes per 4-bank group for both writes and reads.
template <bool ATOMIC>
__global__ __launch_bounds__(256, 2) void gram_kernel(const float* __restrict__ x,
                                                      float* __restrict__ dst) {
    __shared__ __bf16 As[128 * 64];
    __shared__ __bf16 Bs[128 * 64];

    const int kpart = blockIdx.x & (KPARTS - 1);
    const int tile = blockIdx.x >> 5;  // requires KPARTS == 32
    const int i0 = (tile & 3) * 128;
    const int j0 = (tile >> 2) * 128;
    const int kbase0 = kpart * KC;

    const int t = threadIdx.x;
    const int iq = t & 31;  // feature quad within tile
    const int no = t >> 5;  // sample octet 0..7

    const float* pa = x + (size_t)(kbase0 + no * 8) * D + (i0 + iq * 4);
    const float* pb = x + (size_t)(kbase0 + no * 8) * D + (j0 + iq * 4);

    float4 va[8], vb[8];
#pragma unroll
    for (int r = 0; r < 8; ++r) {
        va[r] = *(const float4*)(pa + (size_t)r * D);
        vb[r] = *(const float4*)(pb + (size_t)r * D);
    }

    floatx4 acc[4][4];
#pragma unroll
    for (int a = 0; a < 4; ++a)
#pragma unroll
        for (int b = 0; b < 4; ++b) acc[a][b] = (floatx4)0.0f;

    const int l = t & 63;
    const int wv = t >> 6;
    const int wm = (wv >> 1) * 64;
    const int wn = (wv & 1) * 64;
    const int rl = l & 15;
    const int q = l >> 4;

    for (int c = 0; c < NCHUNK; ++c) {
        __syncthreads();  // previous chunk's LDS reads done
        // stage registers -> LDS (transposed, fp32 -> bf16)
#pragma unroll
        for (int cc = 0; cc < 4; ++cc) {
            bf16x8 wA, wB;
#pragma unroll
            for (int r = 0; r < 8; ++r) {
                wA[r] = (__bf16)(((const float*)&va[r])[cc]);
                wB[r] = (__bf16)(((const float*)&vb[r])[cc]);
            }
            const int fi = iq * 4 + cc;
            const int pc = (no + (fi >> 1)) & 7;
            *(bf16x8*)(As + fi * 64 + pc * 8) = wA;
            *(bf16x8*)(Bs + fi * 64 + pc * 8) = wB;
        }
        // prefetch next chunk while this chunk computes
        if (c + 1 < NCHUNK) {
            const float* na = pa + (size_t)(c + 1) * BK * D;
            const float* nb = pb + (size_t)(c + 1) * BK * D;
#pragma unroll
            for (int r = 0; r < 8; ++r) {
                va[r] = *(const float4*)(na + (size_t)r * D);
                vb[r] = *(const float4*)(nb + (size_t)r * D);
            }
        }
        __syncthreads();  // LDS visible
#pragma unroll
        for (int kk = 0; kk < 2; ++kk) {
            bf16x8 af[4], bfr[4];
#pragma unroll
            for (int tm = 0; tm < 4; ++tm) {
                const int fi = wm + tm * 16 + rl;
                const int pc = ((kk * 4 + q) + (fi >> 1)) & 7;
                af[tm] = *(const bf16x8*)(As + fi * 64 + pc * 8);
            }
#pragma unroll
            for (int tn = 0; tn < 4; ++tn) {
                const int fj = wn + tn * 16 + rl;
                const int pc = ((kk * 4 + q) + (fj >> 1)) & 7;
                bfr[tn] = *(const bf16x8*)(Bs + fj * 64 + pc * 8);
            }
#pragma unroll
            for (int tm = 0; tm < 4; ++tm)
#pragma unroll
                for (int tn = 0; tn < 4; ++tn)
                    acc[tm][tn] = __builtin_amdgcn_mfma_f32_16x16x32_bf16(
                        af[tm], bfr[tn], acc[tm][tn], 0, 0, 0);
        }
    }

    // epilogue: C/D layout col = lane&15, row = (lane>>4)*4 + reg (verified m89/m91)
    if (ATOMIC) {
#pragma unroll
        for (int tm = 0; tm < 4; ++tm)
#pragma unroll
            for (int tn = 0; tn < 4; ++tn)
#pragma unroll
                for (int rr = 0; rr < 4; ++rr) {
                    const int gi = i0 + wm + tm * 16 + q * 4 + rr;
                    const int gj = j0 + wn + tn * 16 + rl;
                    atomicAdd(dst + (size_t)gi * D + gj, acc[tm][tn][rr]);
                }
    } else {
        float* p = dst + (size_t)kpart * (D * D);
#pragma unroll
        for (int tm = 0; tm < 4; ++tm)
#pragma unroll
            for (int tn = 0; tn < 4; ++tn)
#pragma unroll
                for (int rr = 0; rr < 4; ++rr) {
                    const int gi = i0 + wm + tm * 16 + q * 4 + rr;
                    const int gj = j0 + wn + tn * 16 + rl;
                    p[(size_t)gi * D + gj] = acc[tm][tn][rr];
                }
    }
}

// Sum k-partials, apply grad transform. For the atomic fallback (kparts==1, src==out)
// this is a pure elementwise in-place transform.
__global__ __launch_bounds__(256) void finalize_kernel(const float* __restrict__ src, int kparts,
                                                       const float* __restrict__ kappa_p,
                                                       float* __restrict__ out) {
    const int idx4 = blockIdx.x * 256 + threadIdx.x;  // one float4 per thread
    const int base = idx4 * 4;
    float4 s = {0.f, 0.f, 0.f, 0.f};
    for (int p = 0; p < kparts; ++p) {
        const float4 v = *(const float4*)(src + (size_t)p * (D * D) + base);
        s.x += v.x; s.y += v.y; s.z += v.z; s.w += v.w;
    }
    const float kappa = *kappa_p;
    const float invn = 1.0f / (float)NSAMP;
    const int i = base >> 9;
    const int j = base & (D - 1);
    float r[4] = {s.x, s.y, s.z, s.w};
#pragma unroll
    for (int cpt = 0; cpt < 4; ++cpt) {
        const float m = r[cpt] * invn;
        r[cpt] = (i == j + cpt) ? kappa * (m - 1.0f) : (1.0f - kappa) * m;
    }
    float4 o = {r[0], r[1], r[2], r[3]};
    *(float4*)(out + base) = o;
}

extern "C" void kernel_launch(void* const* d_in, const int* in_sizes, int n_in,
                              void* d_out, int out_size, void* d_ws, size_t ws_size,
                              hipStream_t stream) {
    const float* x = (const float*)d_in[0];
    const float* kappa = (const float*)d_in[1];
    float* out = (float*)d_out;

    zero_kernel<<<(out_size + 1023) / 1024, 1024, 0, stream>>>(out, out_size);
    loss_kernel<<<512, 256, 0, stream>>>(x, out);

    const size_t need = (size_t)KPARTS * D * D * sizeof(float);
    if (ws_size >= need) {
        float* parts = (float*)d_ws;
        gram_kernel<false><<<16 * KPARTS, 256, 0, stream>>>(x, parts);
        finalize_kernel<<<(D * D / 4) / 256, 256, 0, stream>>>(parts, KPARTS, kappa, out);
    } else {
        gram_kernel<true><<<16 * KPARTS, 256, 0, stream>>>(x, out);
        finalize_kernel<<<(D * D / 4) / 256, 256, 0, stream>>>(out, 1, kappa, out);
    }
}

// Round 2
// 138.244 us; speedup vs baseline: 1.3485x; 1.3485x over previous
//
#include <hip/hip_runtime.h>
#include <hip/hip_bf16.h>

// DecorrLoss: x (8,4096,512) fp32, kappa scalar ->
//   grad (512,512), correlation_loss (scalar), whitening_loss (scalar)
// out layout: [0..262143] grad, [262144] corr, [262145] whit
//
// Identities used:
//   corr  = sum_n (s2_n^2 - s4_n) / (N d^2)
//   whit  = sum_n (s4_n - 2 s2_n) / (N d^2) + 1/d      (since sum_i (x^2-1)^2 = s4 - 2 s2 + d)
//   grad  = (1-k)/N * gram  off-diag,  k*(gram_ii/N - 1) on diag,  gram = X^T X

#define D 512
#define NSAMP 32768
#define KPARTS 32
#define KC (NSAMP / KPARTS)  // 1024 samples per k-partition
#define BK 64
#define NCHUNK (KC / BK)     // 16 chunks per block
#define LOSS_BLOCKS 2048     // 4 waves/block, 4 rows/wave -> 32768 rows

typedef __bf16 bf16x8 __attribute__((ext_vector_type(8)));
typedef float floatx4 __attribute__((ext_vector_type(4)));

__global__ __launch_bounds__(1024) void zero_kernel(float* out, int n) {
    int i = blockIdx.x * 1024 + threadIdx.x;
    if (i < n) out[i] = 0.0f;
}

// R2: latency-hiding rewrite. 2048 blocks x 4 waves (32 waves/CU), 4 rows/wave,
// all 8 float4 loads issued before any reduce, 4 independent shuffle trees
// interleaved (8-way ILP over ds_swizzle latency). Per-block partial -> ws,
// no global atomics (R1 showed 65us latency-bound: HBM 6.4%, VALU 3.3%).
template <bool ATOMIC>
__global__ __launch_bounds__(256) void loss_kernel(const float* __restrict__ x,
                                                   float2* __restrict__ partials,
                                                   float* __restrict__ out) {
    __shared__ float sA[4], sB[4];
    const int w = threadIdx.x >> 6;
    const int l = threadIdx.x & 63;
    const int gw = blockIdx.x * 4 + w;  // global wave 0..8191
    const float* base = x + (size_t)gw * 4 * D;

    float4 v[8];
#pragma unroll
    for (int r = 0; r < 4; ++r) {
        v[2 * r]     = *(const float4*)(base + (size_t)r * D + l * 4);
        v[2 * r + 1] = *(const float4*)(base + (size_t)r * D + 256 + l * 4);
    }
    float p2[4], p4[4];
#pragma unroll
    for (int r = 0; r < 4; ++r) {
        const float* f = (const float*)&v[2 * r];
        float a2 = 0.f, a4 = 0.f, e;
#pragma unroll
        for (int c = 0; c < 8; ++c) {
            e = f[c] * f[c];
            a2 += e;
            a4 += e * e;
        }
        p2[r] = a2;
        p4[r] = a4;
    }
#pragma unroll
    for (int m = 1; m < 64; m <<= 1) {
#pragma unroll
        for (int r = 0; r < 4; ++r) {
            p2[r] += __shfl_xor(p2[r], m);
            p4[r] += __shfl_xor(p4[r], m);
        }
    }
    float accA = 0.f, accB = 0.f;
#pragma unroll
    for (int r = 0; r < 4; ++r) {
        accA += p2[r] * p2[r] - p4[r];
        accB += p4[r] - 2.0f * p2[r];
    }
    if (l == 0) { sA[w] = accA; sB[w] = accB; }
    __syncthreads();
    if (threadIdx.x == 0) {
        const float bA = sA[0] + sA[1] + sA[2] + sA[3];
        const float bB = sB[0] + sB[1] + sB[2] + sB[3];
        if (ATOMIC) {
            const float SCALE = 1.1641532182693481e-10f;  // 1/(N*d*d) = 2^-33
            atomicAdd(out + D * D, bA * SCALE);
            atomicAdd(out + D * D + 1, bB * SCALE);
            if (blockIdx.x == 0) atomicAdd(out + D * D + 1, 0.001953125f);  // +1/d
        } else {
            partials[blockIdx.x] = make_float2(bA, bB);
        }
    }
}

__global__ __launch_bounds__(256) void scalar_reduce_kernel(const float2* __restrict__ partials,
                                                            float* __restrict__ out) {
    __shared__ float sA[4], sB[4];
    const int w = threadIdx.x >> 6;
    const int l = threadIdx.x & 63;
    float a = 0.f, b = 0.f;
    for (int i = threadIdx.x; i < LOSS_BLOCKS; i += 256) {
        const float2 p = partials[i];
        a += p.x;
        b += p.y;
    }
#pragma unroll
    for (int m = 1; m < 64; m <<= 1) {
        a += __shfl_xor(a, m);
        b += __shfl_xor(b, m);
    }
    if (l == 0) { sA[w] = a; sB[w] = b; }
    __syncthreads();
    if (threadIdx.x == 0) {
        const float SCALE = 1.1641532182693481e-10f;  // 1/(N*d*d) = 2^-33
        out[D * D] = (sA[0] + sA[1] + sA[2] + sA[3]) * SCALE;
        out[D * D + 1] = (sB[0] + sB[1] + sB[2] + sB[3]) * SCALE + 0.001953125f;  // +1/d
    }
}

// Split-K bf16 MFMA Gram. Block = 256 thr (4 waves 2x2, each wave 64x64 via 4x4 of 16x16x32).
// LDS: [feature 0..127][k 0..63] bf16, row stride 128 B, 16B-chunk XOR-ish swizzle
// pc = (k_octet + (feat>>1)) & 7 -> uniform 8 lanes per 4-bank group for both writes and reads.
template <bool ATOMIC>
__global__ __launch_bounds__(256, 2) void gram_kernel(const float* __restrict__ x,
                                                      float* __restrict__ dst) {
    __shared__ __bf16 As[128 * 64];
    __shared__ __bf16 Bs[128 * 64];

    const int kpart = blockIdx.x & (KPARTS - 1);
    const int tile = blockIdx.x >> 5;  // requires KPARTS == 32
    const int i0 = (tile & 3) * 128;
    const int j0 = (tile >> 2) * 128;
    const int kbase0 = kpart * KC;

    const int t = threadIdx.x;
    const int iq = t & 31;  // feature quad within tile
    const int no = t >> 5;  // sample octet 0..7

    const float* pa = x + (size_t)(kbase0 + no * 8) * D + (i0 + iq * 4);
    const float* pb = x + (size_t)(kbase0 + no * 8) * D + (j0 + iq * 4);

    float4 va[8], vb[8];
#pragma unroll
    for (int r = 0; r < 8; ++r) {
        va[r] = *(const float4*)(pa + (size_t)r * D);
        vb[r] = *(const float4*)(pb + (size_t)r * D);
    }

    floatx4 acc[4][4];
#pragma unroll
    for (int a = 0; a < 4; ++a)
#pragma unroll
        for (int b = 0; b < 4; ++b) acc[a][b] = (floatx4)0.0f;

    const int l = t & 63;
    const int wv = t >> 6;
    const int wm = (wv >> 1) * 64;
    const int wn = (wv & 1) * 64;
    const int rl = l & 15;
    const int q = l >> 4;

    for (int c = 0; c < NCHUNK; ++c) {
        __syncthreads();  // previous chunk's LDS reads done
        // stage registers -> LDS (transposed, fp32 -> bf16)
#pragma unroll
        for (int cc = 0; cc < 4; ++cc) {
            bf16x8 wA, wB;
#pragma unroll
            for (int r = 0; r < 8; ++r) {
                wA[r] = (__bf16)(((const float*)&va[r])[cc]);
                wB[r] = (__bf16)(((const float*)&vb[r])[cc]);
            }
            const int fi = iq * 4 + cc;
            const int pc = (no + (fi >> 1)) & 7;
            *(bf16x8*)(As + fi * 64 + pc * 8) = wA;
            *(bf16x8*)(Bs + fi * 64 + pc * 8) = wB;
        }
        // prefetch next chunk while this chunk computes
        if (c + 1 < NCHUNK) {
            const float* na = pa + (size_t)(c + 1) * BK * D;
            const float* nb = pb + (size_t)(c + 1) * BK * D;
#pragma unroll
            for (int r = 0; r < 8; ++r) {
                va[r] = *(const float4*)(na + (size_t)r * D);
                vb[r] = *(const float4*)(nb + (size_t)r * D);
            }
        }
        __syncthreads();  // LDS visible
#pragma unroll
        for (int kk = 0; kk < 2; ++kk) {
            bf16x8 af[4], bfr[4];
#pragma unroll
            for (int tm = 0; tm < 4; ++tm) {
                const int fi = wm + tm * 16 + rl;
                const int pc = ((kk * 4 + q) + (fi >> 1)) & 7;
                af[tm] = *(const bf16x8*)(As + fi * 64 + pc * 8);
            }
#pragma unroll
            for (int tn = 0; tn < 4; ++tn) {
                const int fj = wn + tn * 16 + rl;
                const int pc = ((kk * 4 + q) + (fj >> 1)) & 7;
                bfr[tn] = *(const bf16x8*)(Bs + fj * 64 + pc * 8);
            }
#pragma unroll
            for (int tm = 0; tm < 4; ++tm)
#pragma unroll
                for (int tn = 0; tn < 4; ++tn)
                    acc[tm][tn] = __builtin_amdgcn_mfma_f32_16x16x32_bf16(
                        af[tm], bfr[tn], acc[tm][tn], 0, 0, 0);
        }
    }

    // epilogue: C/D layout col = lane&15, row = (lane>>4)*4 + reg (verified m89/m91)
    if (ATOMIC) {
#pragma unroll
        for (int tm = 0; tm < 4; ++tm)
#pragma unroll
            for (int tn = 0; tn < 4; ++tn)
#pragma unroll
                for (int rr = 0; rr < 4; ++rr) {
                    const int gi = i0 + wm + tm * 16 + q * 4 + rr;
                    const int gj = j0 + wn + tn * 16 + rl;
                    atomicAdd(dst + (size_t)gi * D + gj, acc[tm][tn][rr]);
                }
    } else {
        float* p = dst + (size_t)kpart * (D * D);
#pragma unroll
        for (int tm = 0; tm < 4; ++tm)
#pragma unroll
            for (int tn = 0; tn < 4; ++tn)
#pragma unroll
                for (int rr = 0; rr < 4; ++rr) {
                    const int gi = i0 + wm + tm * 16 + q * 4 + rr;
                    const int gj = j0 + wn + tn * 16 + rl;
                    p[(size_t)gi * D + gj] = acc[tm][tn][rr];
                }
    }
}

// Sum k-partials, apply grad transform. For the atomic fallback (kparts==1, src==out)
// this is a pure elementwise in-place transform.
__global__ __launch_bounds__(256) void finalize_kernel(const float* __restrict__ src, int kparts,
                                                       const float* __restrict__ kappa_p,
                                                       float* __restrict__ out) {
    const int idx4 = blockIdx.x * 256 + threadIdx.x;  // one float4 per thread
    const int base = idx4 * 4;
    float4 s = {0.f, 0.f, 0.f, 0.f};
    for (int p = 0; p < kparts; ++p) {
        const float4 v = *(const float4*)(src + (size_t)p * (D * D) + base);
        s.x += v.x; s.y += v.y; s.z += v.z; s.w += v.w;
    }
    const float kappa = *kappa_p;
    const float invn = 1.0f / (float)NSAMP;
    const int i = base >> 9;
    const int j = base & (D - 1);
    float r[4] = {s.x, s.y, s.z, s.w};
#pragma unroll
    for (int cpt = 0; cpt < 4; ++cpt) {
        const float m = r[cpt] * invn;
        r[cpt] = (i == j + cpt) ? kappa * (m - 1.0f) : (1.0f - kappa) * m;
    }
    float4 o = {r[0], r[1], r[2], r[3]};
    *(float4*)(out + base) = o;
}

extern "C" void kernel_launch(void* const* d_in, const int* in_sizes, int n_in,
                              void* d_out, int out_size, void* d_ws, size_t ws_size,
                              hipStream_t stream) {
    const float* x = (const float*)d_in[0];
    const float* kappa = (const float*)d_in[1];
    float* out = (float*)d_out;

    const size_t gram_bytes = (size_t)KPARTS * D * D * sizeof(float);
    const size_t loss_bytes = (size_t)LOSS_BLOCKS * sizeof(float2);

    if (ws_size >= gram_bytes + loss_bytes) {
        float* parts = (float*)d_ws;
        float2* lpart = (float2*)((char*)d_ws + gram_bytes);
        loss_kernel<false><<<LOSS_BLOCKS, 256, 0, stream>>>(x, lpart, out);
        gram_kernel<false><<<16 * KPARTS, 256, 0, stream>>>(x, parts);
        finalize_kernel<<<(D * D / 4) / 256, 256, 0, stream>>>(parts, KPARTS, kappa, out);
        scalar_reduce_kernel<<<1, 256, 0, stream>>>(lpart, out);
    } else if (ws_size >= loss_bytes) {
        float2* lpart = (float2*)d_ws;
        zero_kernel<<<(out_size + 1023) / 1024, 1024, 0, stream>>>(out, out_size);
        loss_kernel<false><<<LOSS_BLOCKS, 256, 0, stream>>>(x, lpart, out);
        gram_kernel<true><<<16 * KPARTS, 256, 0, stream>>>(x, out);
        finalize_kernel<<<(D * D / 4) / 256, 256, 0, stream>>>(out, 1, kappa, out);
        scalar_reduce_kernel<<<1, 256, 0, stream>>>(lpart, out);
    } else {
        zero_kernel<<<(out_size + 1023) / 1024, 1024, 0, stream>>>(out, out_size);
        loss_kernel<true><<<LOSS_BLOCKS, 256, 0, stream>>>(x, nullptr, out);
        gram_kernel<true><<<16 * KPARTS, 256, 0, stream>>>(x, out);
        finalize_kernel<<<(D * D / 4) / 256, 256, 0, stream>>>(out, 1, kappa, out);
    }
}